// Round 5
// baseline (222.246 us; speedup 1.0000x reference)
//
#include <hip/hip_runtime.h>
#include <hip/hip_fp16.h>

// VoxelHashTable R10: R9 with compile fixes (nontemporal_load needs a clang
// ext-vector type, not HIP float4; stray dummy identifier removed).
// R8 evidence: harness ws-poison fill (512MB @6.6TB/s = 77us) tops the
// profile; query kernel ~65us est. Model: query floor ~= (220MB level0
// L2-miss + 125MB NT out)/6.6TB/s ~= 52us. This round, no precision change:
//   1. Exact-reachable-corner bounds +1 margin: T0 29.6->26.4MB, T1->2.0MB.
//   2. 8 threads/query doing BOTH levels: halves qpts redundancy, shares
//      addr math, 16 independent 8B gathers in flight, 256B/query
//      contiguous NT store (2KB/wave).
//   3. NT loads for read-once streams (qpts, feats), NT stores for tables:
//      keep per-XCD L2 for T0/T1 reuse.

#define TMASK 0xFFFFFu   // TSIZE = 2^20 -> '&' == jnp.mod (floored)
#define PM0 455773u      // 73856093 % 2^20
#define PM1 475301u      // 19349669 % 2^20
#define PM2 655287u      // 83492791 % 2^20

#define BMINX -2.6f
#define BMINY -8.1f
#define BMINZ  0.0f
#define BMAXX  4.6f
#define BMAXY  4.7f
#define BMAXZ  3.1f
#define RES0   0.12f
#define RES1   0.24f

typedef float nfloat4 __attribute__((ext_vector_type(4)));

union H8 {                      // 8 bytes = 4 fp16
    unsigned long long u;
    __half2 h[2];
};

static __device__ __forceinline__ unsigned vhash(int cx, int cy, int cz) {
    return ((unsigned)cx * PM0 + (unsigned)cy * PM1 + (unsigned)cz * PM2) & TMASK;
}

// ---- Pass A (tier1): build fp16 tables ------------------------------------
// 8 lanes per voxel row. Level0: row (ix,iy,iz) -> block(iz) slot0 and
// block(iz-1) slot1 (z+1). Top block's z+1 slot zeroed. Level1: plain rows.
__global__ __launch_bounds__(256) void build_fp16_tables(
    const int* __restrict__ h2v0, const int* __restrict__ h2v1,
    const float* __restrict__ feats0, const float* __restrict__ feats1,
    unsigned char* __restrict__ T0, unsigned char* __restrict__ T1,
    int x0a, int y0a, int z0a, int eya, int eza,
    int x0b, int y0b, int z0b, int eyb, int ezb,
    int R0, int R1)
{
    const int tid = blockIdx.x * 256 + (int)threadIdx.x;
    const int grp = tid >> 3, gt = tid & 7;
    if (grp < R0) {
        const int iz = grp % eza, t = grp / eza, iy = t % eya, ix = t / eya;
        const int v = h2v0[vhash(ix + x0a, iy + y0a, iz + z0a)];
        nfloat4 f = {0.f, 0.f, 0.f, 0.f};
        if (v >= 0)
            f = __builtin_nontemporal_load(
                    (const nfloat4*)(feats0 + (size_t)v * 32 + gt * 4));
        H8 pk;
        pk.h[0] = __floats2half2_rn(f.x, f.y);
        pk.h[1] = __floats2half2_rn(f.z, f.w);
        __builtin_nontemporal_store(pk.u,
            (unsigned long long*)(T0 + (size_t)grp * 128 + gt * 8));
        if (iz > 0)
            __builtin_nontemporal_store(pk.u,
                (unsigned long long*)(T0 + (size_t)(grp - 1) * 128 + 64 + gt * 8));
        if (iz == eza - 1)
            __builtin_nontemporal_store(0ull,
                (unsigned long long*)(T0 + (size_t)grp * 128 + 64 + gt * 8));
    } else if (grp < R0 + R1) {
        const int r = grp - R0;
        const int iz = r % ezb, t = r / ezb, iy = t % eyb, ix = t / eyb;
        const int v = h2v1[vhash(ix + x0b, iy + y0b, iz + z0b)];
        nfloat4 f = {0.f, 0.f, 0.f, 0.f};
        if (v >= 0)
            f = __builtin_nontemporal_load(
                    (const nfloat4*)(feats1 + (size_t)v * 32 + gt * 4));
        H8 pk;
        pk.h[0] = __floats2half2_rn(f.x, f.y);
        pk.h[1] = __floats2half2_rn(f.z, f.w);
        __builtin_nontemporal_store(pk.u,
            (unsigned long long*)(T1 + (size_t)r * 64 + gt * 8));
    }
}

// ---- Main (tier1): 8 threads/query, both levels ---------------------------
// Lane gt owns feature chunk gt (4 floats) for BOTH levels. 16 independent
// 8B gathers issued up front; FMAs after. Output: 256B contiguous per query.
__global__ __launch_bounds__(256) void voxel_query_fp16_v2(
    const float* __restrict__ qpts,
    const unsigned char* __restrict__ T0, const unsigned char* __restrict__ T1,
    int x0a, int y0a, int z0a, int eya, int eza,
    int x0b, int y0b, int z0b, int eyb, int ezb,
    float* __restrict__ out, int M)
{
    const int tid = blockIdx.x * 256 + (int)threadIdx.x;
    const int s  = tid >> 3;
    const int gt = tid & 7;
    if (s >= M) return;

    const float qx = __builtin_nontemporal_load(qpts + 3 * (size_t)s + 0);
    const float qy = __builtin_nontemporal_load(qpts + 3 * (size_t)s + 1);
    const float qz = __builtin_nontemporal_load(qpts + 3 * (size_t)s + 2);
    const int boff = gt * 8;

    // ---------------- level 0 addresses ----------------
    const float sx0 = qx / RES0, sy0 = qy / RES0, sz0 = qz / RES0;
    const float bx0 = floorf(sx0), by0 = floorf(sy0), bz0 = floorf(sz0);
    const float fx0 = sx0 - bx0, fy0 = sy0 - by0, fz0 = sz0 - bz0;
    const int ax = (int)bx0 - x0a, ay = (int)by0 - y0a, az = (int)bz0 - z0a;
    const int a00 = (ax * eya + ay) * eza + az;
    const int a01 = a00 + eza;
    const int a10 = a00 + eya * eza;
    const int a11 = a10 + eza;

    // ---------------- level 1 addresses ----------------
    const float sx1 = qx / RES1, sy1 = qy / RES1, sz1 = qz / RES1;
    const float bx1 = floorf(sx1), by1 = floorf(sy1), bz1 = floorf(sz1);
    const float fx1 = sx1 - bx1, fy1 = sy1 - by1, fz1 = sz1 - bz1;
    const int bx = (int)bx1 - x0b, by = (int)by1 - y0b, bz = (int)bz1 - z0b;
    const int b00 = (bx * eyb + by) * ezb + bz;
    const int b01 = b00 + ezb;
    const int b10 = b00 + eyb * ezb;
    const int b11 = b10 + ezb;

    // ---------------- issue all 16 gathers ----------------
    H8 d[16];
    {
        const unsigned char* p;
        p = T0 + (size_t)a00 * 128 + boff;
        d[0].u = *(const unsigned long long*)p;
        d[1].u = *(const unsigned long long*)(p + 64);
        p = T0 + (size_t)a01 * 128 + boff;
        d[2].u = *(const unsigned long long*)p;
        d[3].u = *(const unsigned long long*)(p + 64);
        p = T0 + (size_t)a10 * 128 + boff;
        d[4].u = *(const unsigned long long*)p;
        d[5].u = *(const unsigned long long*)(p + 64);
        p = T0 + (size_t)a11 * 128 + boff;
        d[6].u = *(const unsigned long long*)p;
        d[7].u = *(const unsigned long long*)(p + 64);
        // level1: rows are 64B; z+1 row is the next cell (+64B)
        p = T1 + (size_t)b00 * 64 + boff;
        d[8].u  = *(const unsigned long long*)p;
        d[9].u  = *(const unsigned long long*)(p + 64);
        p = T1 + (size_t)b01 * 64 + boff;
        d[10].u = *(const unsigned long long*)p;
        d[11].u = *(const unsigned long long*)(p + 64);
        p = T1 + (size_t)b10 * 64 + boff;
        d[12].u = *(const unsigned long long*)p;
        d[13].u = *(const unsigned long long*)(p + 64);
        p = T1 + (size_t)b11 * 64 + boff;
        d[14].u = *(const unsigned long long*)p;
        d[15].u = *(const unsigned long long*)(p + 64);
    }

    // ---------------- weights ----------------
    const float wx0 = 1.0f - fx0, wy0 = 1.0f - fy0, wz0 = 1.0f - fz0;
    const float wx1 = 1.0f - fx1, wy1 = 1.0f - fy1, wz1 = 1.0f - fz1;
    float w0[8], w1[8];
    w0[0] = wx0 * wy0 * wz0; w0[1] = wx0 * wy0 * fz0;
    w0[2] = wx0 * fy0 * wz0; w0[3] = wx0 * fy0 * fz0;
    w0[4] = fx0 * wy0 * wz0; w0[5] = fx0 * wy0 * fz0;
    w0[6] = fx0 * fy0 * wz0; w0[7] = fx0 * fy0 * fz0;
    w1[0] = wx1 * wy1 * wz1; w1[1] = wx1 * wy1 * fz1;
    w1[2] = wx1 * fy1 * wz1; w1[3] = wx1 * fy1 * fz1;
    w1[4] = fx1 * wy1 * wz1; w1[5] = fx1 * wy1 * fz1;
    w1[6] = fx1 * fy1 * wz1; w1[7] = fx1 * fy1 * fz1;

    nfloat4 acc0 = {0.f, 0.f, 0.f, 0.f};
    nfloat4 acc1 = {0.f, 0.f, 0.f, 0.f};
    #pragma unroll
    for (int c = 0; c < 8; ++c) {
        const float2 u0 = __half22float2(d[c].h[0]);
        const float2 v0 = __half22float2(d[c].h[1]);
        acc0.x = fmaf(w0[c], u0.x, acc0.x);
        acc0.y = fmaf(w0[c], u0.y, acc0.y);
        acc0.z = fmaf(w0[c], v0.x, acc0.z);
        acc0.w = fmaf(w0[c], v0.y, acc0.w);
        const float2 u1 = __half22float2(d[8 + c].h[0]);
        const float2 v1 = __half22float2(d[8 + c].h[1]);
        acc1.x = fmaf(w1[c], u1.x, acc1.x);
        acc1.y = fmaf(w1[c], u1.y, acc1.y);
        acc1.z = fmaf(w1[c], v1.x, acc1.z);
        acc1.w = fmaf(w1[c], v1.y, acc1.w);
    }

    // 256B contiguous per query (2KB/wave) streaming stores
    float* o = out + (size_t)s * 64;
    __builtin_nontemporal_store(acc0, (nfloat4*)(o) + gt);
    __builtin_nontemporal_store(acc1, (nfloat4*)(o + 32) + gt);
}

// ============================================================================
// Tier 2 (R6): int dense tables + f32 gathers, original order
// ============================================================================
__global__ __launch_bounds__(256) void build_dense(
    const int* __restrict__ h2v0, const int* __restrict__ h2v1,
    int* __restrict__ dense0, int* __restrict__ dense1,
    int x0a, int y0a, int z0a, int eya, int eza,
    int x0b, int y0b, int z0b, int eyb, int ezb,
    int D0, int D1)
{
    const int i = blockIdx.x * blockDim.x + threadIdx.x;
    if (i < D0) {
        const int iz = i % eza, t = i / eza, iy = t % eya, ix = t / eya;
        dense0[i] = h2v0[vhash(ix + x0a, iy + y0a, iz + z0a)];
    } else if (i < D0 + D1) {
        const int j = i - D0;
        const int iz = j % ezb, t = j / ezb, iy = t % eyb, ix = t / eyb;
        dense1[j] = h2v1[vhash(ix + x0b, iy + y0b, iz + z0b)];
    }
}

__global__ __launch_bounds__(256) void voxel_query_direct(
    const float* __restrict__ qpts,
    const float* __restrict__ feats0, const float* __restrict__ feats1,
    const int*   __restrict__ h2v0,   const int*   __restrict__ h2v1,
    const int*   __restrict__ dense0, const int*   __restrict__ dense1,
    int x0a, int y0a, int z0a, int exa, int eya, int eza,
    int x0b, int y0b, int z0b, int exb, int eyb, int ezb,
    float* __restrict__ out, int M)
{
    const int tid = blockIdx.x * 256 + (int)threadIdx.x;
    const int g  = tid >> 3;
    const int gt = tid & 7;
    const int s  = g >> 1;
    const int level = g & 1;
    if (s >= M) return;

    const float qx = qpts[3 * (size_t)s + 0];
    const float qy = qpts[3 * (size_t)s + 1];
    const float qz = qpts[3 * (size_t)s + 2];

    const float res = level ? RES1 : RES0;
    const float* __restrict__ feats = level ? feats1 : feats0;
    const int*   __restrict__ h2v   = level ? h2v1   : h2v0;
    const int*   __restrict__ dense = level ? dense1 : dense0;
    const int x0 = level ? x0b : x0a, y0 = level ? y0b : y0a, z0 = level ? z0b : z0a;
    const int ex = level ? exb : exa, ey = level ? eyb : eya, ez = level ? ezb : eza;

    const float sx = qx / res, sy = qy / res, sz = qz / res;
    const float bx = floorf(sx), by = floorf(sy), bz = floorf(sz);
    const float fx = sx - bx,  fy = sy - by,  fz = sz - bz;

    const int ox = (gt >> 2) & 1, oy = (gt >> 1) & 1, oz = gt & 1;
    const int cx = (int)bx + ox;
    const int cy = (int)by + oy;
    const int cz = (int)bz + oz;

    int v;
    if (cx >= x0 && cx < x0 + ex && cy >= y0 && cy < y0 + ey &&
        cz >= z0 && cz < z0 + ez) {
        v = dense[((size_t)(cx - x0) * ey + (cy - y0)) * ez + (cz - z0)];
    } else {
        v = h2v[vhash(cx, cy, cz)];
    }

    float w = (ox ? fx : 1.0f - fx) * (oy ? fy : 1.0f - fy);
    w *= (oz ? fz : 1.0f - fz);

    nfloat4 acc = {0.0f, 0.0f, 0.0f, 0.0f};
    #pragma unroll
    for (int c = 0; c < 8; ++c) {
        const int   vc = __shfl(v, c, 8);
        const float wc = __shfl(w, c, 8);
        if (vc >= 0) {
            const nfloat4 f4 = ((const nfloat4*)(feats + (size_t)vc * 32))[gt];
            acc += wc * f4;
        }
    }
    __builtin_nontemporal_store(
        acc, (nfloat4*)(out + (size_t)s * 64 + level * 32) + gt);
}

// ---- Tier 3: raw hash fallback --------------------------------------------
__global__ __launch_bounds__(256) void voxel_hash_query_f32(
    const float* __restrict__ qpts,
    const float* __restrict__ feats0, const float* __restrict__ feats1,
    const int*   __restrict__ h2v0,   const int*   __restrict__ h2v1,
    float* __restrict__ out, int M)
{
    const int tid = blockIdx.x * blockDim.x + threadIdx.x;
    const int group = tid >> 3, gt = tid & 7;
    const int m = group >> 1, level = group & 1;
    if (m >= M) return;
    const float res = level ? RES1 : RES0;
    const float* __restrict__ feats = level ? feats1 : feats0;
    const int*   __restrict__ h2v   = level ? h2v1   : h2v0;
    const float qx = qpts[3 * (size_t)m], qy = qpts[3 * (size_t)m + 1],
                qz = qpts[3 * (size_t)m + 2];
    const float sx = qx / res, sy = qy / res, sz = qz / res;
    const float bx = floorf(sx), by = floorf(sy), bz = floorf(sz);
    const float fx = sx - bx, fy = sy - by, fz = sz - bz;
    const int ox = (gt >> 2) & 1, oy = (gt >> 1) & 1, oz = gt & 1;
    const int v = h2v[vhash((int)bx + ox, (int)by + oy, (int)bz + oz)];
    float w = (ox ? fx : 1.0f - fx) * (oy ? fy : 1.0f - fy);
    w *= (oz ? fz : 1.0f - fz);
    nfloat4 acc = {0.f, 0.f, 0.f, 0.f};
    #pragma unroll
    for (int c = 0; c < 8; ++c) {
        const int vc = __shfl(v, c, 8);
        const float wc = __shfl(w, c, 8);
        if (vc >= 0) {
            const nfloat4 f4 = ((const nfloat4*)(feats + (size_t)vc * 32))[gt];
            acc += wc * f4;
        }
    }
    ((nfloat4*)(out + (size_t)m * 64 + level * 32))[gt] = acc;
}

extern "C" void kernel_launch(void* const* d_in, const int* in_sizes, int n_in,
                              void* d_out, int out_size, void* d_ws, size_t ws_size,
                              hipStream_t stream) {
    const float* qpts   = (const float*)d_in[0];
    const float* feats0 = (const float*)d_in[1];
    const float* feats1 = (const float*)d_in[2];
    const int*   h2v0   = (const int*)d_in[3];
    const int*   h2v1   = (const int*)d_in[4];
    float* out = (float*)d_out;
    const int M = in_sizes[0] / 3;

    // Exact reachable corner range + 1 safety margin per side.
    // base = floor(q/res), q in [bmin, bmax) => base in
    // [floor(bmin/res), floor(bmax/res)]; corner = base or base+1.
    const float bmin[3] = {BMINX, BMINY, BMINZ};
    const float bmax[3] = {BMAXX, BMAXY, BMAXZ};
    int lo0[3], ex0[3], lo1[3], ex1[3];
    for (int d = 0; d < 3; ++d) {
        lo0[d] = (int)floorf(bmin[d] / RES0) - 1;
        ex0[d] = ((int)floorf(bmax[d] / RES0) + 2) - lo0[d] + 1;
        lo1[d] = (int)floorf(bmin[d] / RES1) - 1;
        ex1[d] = ((int)floorf(bmax[d] / RES1) + 2) - lo1[d] + 1;
    }
    const int R0 = ex0[0] * ex0[1] * ex0[2];   // level0 blocks (128B each)
    const int R1 = ex1[0] * ex1[1] * ex1[2];   // level1 rows (64B each)

    // ---- tier 1: fp16 tables ----
    {
        char* p = (char*)d_ws;
        unsigned char* T0 = (unsigned char*)p;  p += (size_t)R0 * 128;
        unsigned char* T1 = (unsigned char*)p;  p += (size_t)R1 * 64;
        const size_t need = (size_t)(p - (char*)d_ws);
        if (ws_size >= need) {
            const int gBuild = (int)((8LL * (R0 + R1) + 255) / 256);
            build_fp16_tables<<<gBuild, 256, 0, stream>>>(
                h2v0, h2v1, feats0, feats1, T0, T1,
                lo0[0], lo0[1], lo0[2], ex0[1], ex0[2],
                lo1[0], lo1[1], lo1[2], ex1[1], ex1[2],
                R0, R1);
            const int nbQ = (int)((8LL * M + 255) / 256);
            voxel_query_fp16_v2<<<nbQ, 256, 0, stream>>>(
                qpts, T0, T1,
                lo0[0], lo0[1], lo0[2], ex0[1], ex0[2],
                lo1[0], lo1[1], lo1[2], ex1[1], ex1[2],
                out, M);
            return;
        }
    }

    const long long threads_needed = 16LL * M;
    const int nb = (int)((threads_needed + 255) / 256);

    // ---- tier 2: R6 int-dense path ----
    {
        char* p = (char*)d_ws;
        int* dense0 = (int*)p;                 p += (size_t)R0 * 4;
        int* dense1 = (int*)p;                 p += (size_t)R1 * 4;
        const size_t need = (size_t)(p - (char*)d_ws);
        if (ws_size >= need) {
            const int gA = (R0 + R1 + 255) / 256;
            build_dense<<<gA, 256, 0, stream>>>(h2v0, h2v1, dense0, dense1,
                                                lo0[0], lo0[1], lo0[2], ex0[1], ex0[2],
                                                lo1[0], lo1[1], lo1[2], ex1[1], ex1[2],
                                                R0, R1);
            voxel_query_direct<<<nb, 256, 0, stream>>>(
                qpts, feats0, feats1, h2v0, h2v1, dense0, dense1,
                lo0[0], lo0[1], lo0[2], ex0[0], ex0[1], ex0[2],
                lo1[0], lo1[1], lo1[2], ex1[0], ex1[1], ex1[2],
                out, M);
            return;
        }
    }

    // ---- tier 3: raw hash ----
    voxel_hash_query_f32<<<nb, 256, 0, stream>>>(qpts, feats0, feats1,
                                                 h2v0, h2v1, out, M);
}

// Round 6
// 219.785 us; speedup vs baseline: 1.0112x; 1.0112x over previous
//
#include <hip/hip_runtime.h>
#include <hip/hip_fp16.h>

// VoxelHashTable R11: revert query to the proven R8 16-thread/query
// structure; keep R10's validated trims.
// R10 post-mortem: 8-thread/query "MLP" restructure regressed (VGPR=32
// forced the compiler to serialize the 16-gather burst; R8's 16-thread
// structure hides latency via TLP at VGPR=16/high occupancy and already
// sits near the random-128B-line BW ceiling: ~274MB @ ~4.3TB/s ~= 64us).
// Kept from R10 (hardware-validated): exact-corner bounds (T0 26.4MB,
// T1 2.0MB; FETCH 149MB), NT build loads/stores, NT qpts loads.
//   - T0 (level0): per-voxel 128B pair-block = fp16 rows (z, z+1) ->
//     4 aligned fully-used 128B lines per query-level.
//   - T1 (level1): plain fp16 64B rows, ~2MB -> per-XCD L2 resident.
//   - Invalid cells stored as zeros: no validity branch/shfl/hash in the
//     hot kernel. Output: coalesced 1KB/wave NT stores, original order.

#define TMASK 0xFFFFFu   // TSIZE = 2^20 -> '&' == jnp.mod (floored)
#define PM0 455773u      // 73856093 % 2^20
#define PM1 475301u      // 19349669 % 2^20
#define PM2 655287u      // 83492791 % 2^20

#define BMINX -2.6f
#define BMINY -8.1f
#define BMINZ  0.0f
#define BMAXX  4.6f
#define BMAXY  4.7f
#define BMAXZ  3.1f
#define RES0   0.12f
#define RES1   0.24f

typedef float nfloat4 __attribute__((ext_vector_type(4)));

union H8 {                      // 8 bytes = 4 fp16
    unsigned long long u;
    __half2 h[2];
};

static __device__ __forceinline__ unsigned vhash(int cx, int cy, int cz) {
    return ((unsigned)cx * PM0 + (unsigned)cy * PM1 + (unsigned)cz * PM2) & TMASK;
}

// ---- Pass A (tier1): build fp16 tables ------------------------------------
// 8 lanes per voxel row. Level0: row (ix,iy,iz) -> block(iz) slot0 and
// block(iz-1) slot1 (z+1). Top block's z+1 slot zeroed. Level1: plain rows.
__global__ __launch_bounds__(256) void build_fp16_tables(
    const int* __restrict__ h2v0, const int* __restrict__ h2v1,
    const float* __restrict__ feats0, const float* __restrict__ feats1,
    unsigned char* __restrict__ T0, unsigned char* __restrict__ T1,
    int x0a, int y0a, int z0a, int eya, int eza,
    int x0b, int y0b, int z0b, int eyb, int ezb,
    int R0, int R1)
{
    const int tid = blockIdx.x * 256 + (int)threadIdx.x;
    const int grp = tid >> 3, gt = tid & 7;
    if (grp < R0) {
        const int iz = grp % eza, t = grp / eza, iy = t % eya, ix = t / eya;
        const int v = h2v0[vhash(ix + x0a, iy + y0a, iz + z0a)];
        nfloat4 f = {0.f, 0.f, 0.f, 0.f};
        if (v >= 0)
            f = __builtin_nontemporal_load(
                    (const nfloat4*)(feats0 + (size_t)v * 32 + gt * 4));
        H8 pk;
        pk.h[0] = __floats2half2_rn(f.x, f.y);
        pk.h[1] = __floats2half2_rn(f.z, f.w);
        __builtin_nontemporal_store(pk.u,
            (unsigned long long*)(T0 + (size_t)grp * 128 + gt * 8));
        if (iz > 0)
            __builtin_nontemporal_store(pk.u,
                (unsigned long long*)(T0 + (size_t)(grp - 1) * 128 + 64 + gt * 8));
        if (iz == eza - 1)
            __builtin_nontemporal_store(0ull,
                (unsigned long long*)(T0 + (size_t)grp * 128 + 64 + gt * 8));
    } else if (grp < R0 + R1) {
        const int r = grp - R0;
        const int iz = r % ezb, t = r / ezb, iy = t % eyb, ix = t / eyb;
        const int v = h2v1[vhash(ix + x0b, iy + y0b, iz + z0b)];
        nfloat4 f = {0.f, 0.f, 0.f, 0.f};
        if (v >= 0)
            f = __builtin_nontemporal_load(
                    (const nfloat4*)(feats1 + (size_t)v * 32 + gt * 4));
        H8 pk;
        pk.h[0] = __floats2half2_rn(f.x, f.y);
        pk.h[1] = __floats2half2_rn(f.z, f.w);
        __builtin_nontemporal_store(pk.u,
            (unsigned long long*)(T1 + (size_t)r * 64 + gt * 8));
    }
}

// ---- Main (tier1): R8 structure — 16 threads/query (2 levels x 8 lanes) ---
// Unified addressing: addr = T + cell*S + zslot*64 + gt*8
// (S=128 level0 pair-block, 64 level1). No branches, no shfl, no hash.
__global__ __launch_bounds__(256) void voxel_query_fp16(
    const float* __restrict__ qpts,
    const unsigned char* __restrict__ T0, const unsigned char* __restrict__ T1,
    int x0a, int y0a, int z0a, int eya, int eza,
    int x0b, int y0b, int z0b, int eyb, int ezb,
    float* __restrict__ out, int M)
{
    const int tid = blockIdx.x * 256 + (int)threadIdx.x;
    const int g  = tid >> 3;
    const int gt = tid & 7;
    const int s  = g >> 1;
    const int level = g & 1;
    if (s >= M) return;

    const float qx = __builtin_nontemporal_load(qpts + 3 * (size_t)s + 0);
    const float qy = __builtin_nontemporal_load(qpts + 3 * (size_t)s + 1);
    const float qz = __builtin_nontemporal_load(qpts + 3 * (size_t)s + 2);

    const float res = level ? RES1 : RES0;
    const unsigned char* __restrict__ T = level ? T1 : T0;
    const int S  = level ? 64 : 128;
    const int x0 = level ? x0b : x0a, y0 = level ? y0b : y0a, z0 = level ? z0b : z0a;
    const int ey = level ? eyb : eya, ez = level ? ezb : eza;

    // exact f32 division to match reference floor/frac bitwise
    const float sx = qx / res, sy = qy / res, sz = qz / res;
    const float bx = floorf(sx), by = floorf(sy), bz = floorf(sz);
    const float fx = sx - bx,  fy = sy - by,  fz = sz - bz;

    // margin-1 tables guarantee all 8 corners are in-bounds
    const int ibx = (int)bx - x0, iby = (int)by - y0, ibz = (int)bz - z0;
    const int c00 = (ibx * ey + iby) * ez + ibz;
    const int c01 = c00 + ez;
    const int c10 = c00 + ey * ez;
    const int c11 = c10 + ez;

    const float wx0 = 1.0f - fx, wy0 = 1.0f - fy, wz0 = 1.0f - fz;
    const int boff = gt * 8;

    nfloat4 acc = {0.0f, 0.0f, 0.0f, 0.0f};

    // corner order matches reference OFFSETS: (ox,oy,oz) lexicographic
    #define ACC_CORNER(cell, wxy)                                              \
    do {                                                                       \
        const unsigned char* p = T + (size_t)(cell) * S + boff;                \
        H8 d0, d1;                                                             \
        d0.u = *(const unsigned long long*)p;                                  \
        d1.u = *(const unsigned long long*)(p + 64);                           \
        const float w0 = (wxy) * wz0, w1 = (wxy) * fz;                         \
        {                                                                      \
            const float2 u = __half22float2(d0.h[0]);                          \
            const float2 v = __half22float2(d0.h[1]);                          \
            acc.x = fmaf(w0, u.x, acc.x); acc.y = fmaf(w0, u.y, acc.y);        \
            acc.z = fmaf(w0, v.x, acc.z); acc.w = fmaf(w0, v.y, acc.w);        \
        }                                                                      \
        {                                                                      \
            const float2 u = __half22float2(d1.h[0]);                          \
            const float2 v = __half22float2(d1.h[1]);                          \
            acc.x = fmaf(w1, u.x, acc.x); acc.y = fmaf(w1, u.y, acc.y);        \
            acc.z = fmaf(w1, v.x, acc.z); acc.w = fmaf(w1, v.y, acc.w);        \
        }                                                                      \
    } while (0)

    ACC_CORNER(c00, wx0 * wy0);
    ACC_CORNER(c01, wx0 * fy);
    ACC_CORNER(c10, fx * wy0);
    ACC_CORNER(c11, fx * fy);
    #undef ACC_CORNER

    // streaming full-line store in original query order (1KB/wave)
    __builtin_nontemporal_store(
        acc, (nfloat4*)(out + (size_t)s * 64 + level * 32) + gt);
}

// ============================================================================
// Tier 2 (R6): int dense tables + f32 gathers, original order
// ============================================================================
__global__ __launch_bounds__(256) void build_dense(
    const int* __restrict__ h2v0, const int* __restrict__ h2v1,
    int* __restrict__ dense0, int* __restrict__ dense1,
    int x0a, int y0a, int z0a, int eya, int eza,
    int x0b, int y0b, int z0b, int eyb, int ezb,
    int D0, int D1)
{
    const int i = blockIdx.x * blockDim.x + threadIdx.x;
    if (i < D0) {
        const int iz = i % eza, t = i / eza, iy = t % eya, ix = t / eya;
        dense0[i] = h2v0[vhash(ix + x0a, iy + y0a, iz + z0a)];
    } else if (i < D0 + D1) {
        const int j = i - D0;
        const int iz = j % ezb, t = j / ezb, iy = t % eyb, ix = t / eyb;
        dense1[j] = h2v1[vhash(ix + x0b, iy + y0b, iz + z0b)];
    }
}

__global__ __launch_bounds__(256) void voxel_query_direct(
    const float* __restrict__ qpts,
    const float* __restrict__ feats0, const float* __restrict__ feats1,
    const int*   __restrict__ h2v0,   const int*   __restrict__ h2v1,
    const int*   __restrict__ dense0, const int*   __restrict__ dense1,
    int x0a, int y0a, int z0a, int exa, int eya, int eza,
    int x0b, int y0b, int z0b, int exb, int eyb, int ezb,
    float* __restrict__ out, int M)
{
    const int tid = blockIdx.x * 256 + (int)threadIdx.x;
    const int g  = tid >> 3;
    const int gt = tid & 7;
    const int s  = g >> 1;
    const int level = g & 1;
    if (s >= M) return;

    const float qx = qpts[3 * (size_t)s + 0];
    const float qy = qpts[3 * (size_t)s + 1];
    const float qz = qpts[3 * (size_t)s + 2];

    const float res = level ? RES1 : RES0;
    const float* __restrict__ feats = level ? feats1 : feats0;
    const int*   __restrict__ h2v   = level ? h2v1   : h2v0;
    const int*   __restrict__ dense = level ? dense1 : dense0;
    const int x0 = level ? x0b : x0a, y0 = level ? y0b : y0a, z0 = level ? z0b : z0a;
    const int ex = level ? exb : exa, ey = level ? eyb : eya, ez = level ? ezb : eza;

    const float sx = qx / res, sy = qy / res, sz = qz / res;
    const float bx = floorf(sx), by = floorf(sy), bz = floorf(sz);
    const float fx = sx - bx,  fy = sy - by,  fz = sz - bz;

    const int ox = (gt >> 2) & 1, oy = (gt >> 1) & 1, oz = gt & 1;
    const int cx = (int)bx + ox;
    const int cy = (int)by + oy;
    const int cz = (int)bz + oz;

    int v;
    if (cx >= x0 && cx < x0 + ex && cy >= y0 && cy < y0 + ey &&
        cz >= z0 && cz < z0 + ez) {
        v = dense[((size_t)(cx - x0) * ey + (cy - y0)) * ez + (cz - z0)];
    } else {
        v = h2v[vhash(cx, cy, cz)];
    }

    float w = (ox ? fx : 1.0f - fx) * (oy ? fy : 1.0f - fy);
    w *= (oz ? fz : 1.0f - fz);

    nfloat4 acc = {0.0f, 0.0f, 0.0f, 0.0f};
    #pragma unroll
    for (int c = 0; c < 8; ++c) {
        const int   vc = __shfl(v, c, 8);
        const float wc = __shfl(w, c, 8);
        if (vc >= 0) {
            const nfloat4 f4 = ((const nfloat4*)(feats + (size_t)vc * 32))[gt];
            acc += wc * f4;
        }
    }
    __builtin_nontemporal_store(
        acc, (nfloat4*)(out + (size_t)s * 64 + level * 32) + gt);
}

// ---- Tier 3: raw hash fallback --------------------------------------------
__global__ __launch_bounds__(256) void voxel_hash_query_f32(
    const float* __restrict__ qpts,
    const float* __restrict__ feats0, const float* __restrict__ feats1,
    const int*   __restrict__ h2v0,   const int*   __restrict__ h2v1,
    float* __restrict__ out, int M)
{
    const int tid = blockIdx.x * blockDim.x + threadIdx.x;
    const int group = tid >> 3, gt = tid & 7;
    const int m = group >> 1, level = group & 1;
    if (m >= M) return;
    const float res = level ? RES1 : RES0;
    const float* __restrict__ feats = level ? feats1 : feats0;
    const int*   __restrict__ h2v   = level ? h2v1   : h2v0;
    const float qx = qpts[3 * (size_t)m], qy = qpts[3 * (size_t)m + 1],
                qz = qpts[3 * (size_t)m + 2];
    const float sx = qx / res, sy = qy / res, sz = qz / res;
    const float bx = floorf(sx), by = floorf(sy), bz = floorf(sz);
    const float fx = sx - bx, fy = sy - by, fz = sz - bz;
    const int ox = (gt >> 2) & 1, oy = (gt >> 1) & 1, oz = gt & 1;
    const int v = h2v[vhash((int)bx + ox, (int)by + oy, (int)bz + oz)];
    float w = (ox ? fx : 1.0f - fx) * (oy ? fy : 1.0f - fy);
    w *= (oz ? fz : 1.0f - fz);
    nfloat4 acc = {0.f, 0.f, 0.f, 0.f};
    #pragma unroll
    for (int c = 0; c < 8; ++c) {
        const int vc = __shfl(v, c, 8);
        const float wc = __shfl(w, c, 8);
        if (vc >= 0) {
            const nfloat4 f4 = ((const nfloat4*)(feats + (size_t)vc * 32))[gt];
            acc += wc * f4;
        }
    }
    ((nfloat4*)(out + (size_t)m * 64 + level * 32))[gt] = acc;
}

extern "C" void kernel_launch(void* const* d_in, const int* in_sizes, int n_in,
                              void* d_out, int out_size, void* d_ws, size_t ws_size,
                              hipStream_t stream) {
    const float* qpts   = (const float*)d_in[0];
    const float* feats0 = (const float*)d_in[1];
    const float* feats1 = (const float*)d_in[2];
    const int*   h2v0   = (const int*)d_in[3];
    const int*   h2v1   = (const int*)d_in[4];
    float* out = (float*)d_out;
    const int M = in_sizes[0] / 3;

    // Exact reachable corner range + 1 safety margin per side.
    // base = floor(q/res), q in [bmin, bmax) => base in
    // [floor(bmin/res), floor(bmax/res)]; corner = base or base+1.
    const float bmin[3] = {BMINX, BMINY, BMINZ};
    const float bmax[3] = {BMAXX, BMAXY, BMAXZ};
    int lo0[3], ex0[3], lo1[3], ex1[3];
    for (int d = 0; d < 3; ++d) {
        lo0[d] = (int)floorf(bmin[d] / RES0) - 1;
        ex0[d] = ((int)floorf(bmax[d] / RES0) + 2) - lo0[d] + 1;
        lo1[d] = (int)floorf(bmin[d] / RES1) - 1;
        ex1[d] = ((int)floorf(bmax[d] / RES1) + 2) - lo1[d] + 1;
    }
    const int R0 = ex0[0] * ex0[1] * ex0[2];   // level0 blocks (128B each)
    const int R1 = ex1[0] * ex1[1] * ex1[2];   // level1 rows (64B each)

    const long long threads_needed = 16LL * M;
    const int nb = (int)((threads_needed + 255) / 256);

    // ---- tier 1: fp16 tables ----
    {
        char* p = (char*)d_ws;
        unsigned char* T0 = (unsigned char*)p;  p += (size_t)R0 * 128;
        unsigned char* T1 = (unsigned char*)p;  p += (size_t)R1 * 64;
        const size_t need = (size_t)(p - (char*)d_ws);
        if (ws_size >= need) {
            const int gBuild = (int)((8LL * (R0 + R1) + 255) / 256);
            build_fp16_tables<<<gBuild, 256, 0, stream>>>(
                h2v0, h2v1, feats0, feats1, T0, T1,
                lo0[0], lo0[1], lo0[2], ex0[1], ex0[2],
                lo1[0], lo1[1], lo1[2], ex1[1], ex1[2],
                R0, R1);
            voxel_query_fp16<<<nb, 256, 0, stream>>>(
                qpts, T0, T1,
                lo0[0], lo0[1], lo0[2], ex0[1], ex0[2],
                lo1[0], lo1[1], lo1[2], ex1[1], ex1[2],
                out, M);
            return;
        }
    }

    // ---- tier 2: R6 int-dense path ----
    {
        char* p = (char*)d_ws;
        int* dense0 = (int*)p;                 p += (size_t)R0 * 4;
        int* dense1 = (int*)p;                 p += (size_t)R1 * 4;
        const size_t need = (size_t)(p - (char*)d_ws);
        if (ws_size >= need) {
            const int gA = (R0 + R1 + 255) / 256;
            build_dense<<<gA, 256, 0, stream>>>(h2v0, h2v1, dense0, dense1,
                                                lo0[0], lo0[1], lo0[2], ex0[1], ex0[2],
                                                lo1[0], lo1[1], lo1[2], ex1[1], ex1[2],
                                                R0, R1);
            voxel_query_direct<<<nb, 256, 0, stream>>>(
                qpts, feats0, feats1, h2v0, h2v1, dense0, dense1,
                lo0[0], lo0[1], lo0[2], ex0[0], ex0[1], ex0[2],
                lo1[0], lo1[1], lo1[2], ex1[0], ex1[1], ex1[2],
                out, M);
            return;
        }
    }

    // ---- tier 3: raw hash ----
    voxel_hash_query_f32<<<nb, 256, 0, stream>>>(qpts, feats0, feats1,
                                                 h2v0, h2v1, out, M);
}